// Round 1
// baseline (170.871 us; speedup 1.0000x reference)
//
#include <hip/hip_runtime.h>
#include <stdint.h>

#define NB 32
#define NM 6300
#define NC 80
#define NTOP 1000
#define NPAD 1024
#define NSORT 8192

static constexpr float IMGSZ   = 320.0f;
static constexpr float CONF_TH = 0.05f;
static constexpr float NMS_TH  = 0.6f;
static constexpr float EPSF    = 1e-10f;

// ---- workspace layout (bytes) ----
static constexpr size_t OFF_SCORES = 0;                                    // f32 [NB*NM]
static constexpr size_t OFF_LABELS = OFF_SCORES + (size_t)NB * NM * 4;     // i32 [NB*NM]
static constexpr size_t OFF_TIDX   = OFF_LABELS + (size_t)NB * NM * 4;     // i32 [NB*NPAD]
static constexpr size_t OFF_NBOX   = OFF_TIDX   + (size_t)NB * NPAD * 4;   // f32 [NB*NPAD*4]
static constexpr size_t OFF_NLAB   = OFF_NBOX   + (size_t)NB * NPAD * 16;  // i32 [NB*NPAD]
static constexpr size_t OFF_SUP    = ((OFF_NLAB + (size_t)NB * NPAD * 4) + 1023) & ~(size_t)1023; // u64 [NB*16*16*64]

// ---------------------------------------------------------------------------
// K1: per-anchor score = sigmoid(conf) * max(softmax(cls)), label = argmax.
// 16 lanes per anchor; lanes read consecutive classes (coalesced).
// ---------------------------------------------------------------------------
__global__ __launch_bounds__(256) void k_score(const float* __restrict__ conf,
                                               const float* __restrict__ cls,
                                               float* __restrict__ scores,
                                               int* __restrict__ labels) {
#pragma clang fp contract(off)
    int t = blockIdx.x * blockDim.x + threadIdx.x;
    int a = t >> 4;          // anchor index in [0, NB*NM)
    int l = t & 15;
    if (a >= NB * NM) return;
    const float* row = cls + (size_t)a * NC;

    float v[5];
#pragma unroll
    for (int k = 0; k < 5; ++k) v[k] = row[l + 16 * k];

    // local max/argmax (ties -> lowest class index)
    float bv = v[0];
    int bi = l;
#pragma unroll
    for (int k = 1; k < 5; ++k) {
        int c = l + 16 * k;
        if (v[k] > bv) { bv = v[k]; bi = c; }
    }
    // 16-lane butterfly reduce (max value, min index on ties)
#pragma unroll
    for (int m = 1; m < 16; m <<= 1) {
        float ov = __shfl_xor(bv, m, 16);
        int   oi = __shfl_xor(bi, m, 16);
        if (ov > bv || (ov == bv && oi < bi)) { bv = ov; bi = oi; }
    }
    // sum of exp(x - max)
    float s = 0.0f;
#pragma unroll
    for (int k = 0; k < 5; ++k) s += expf(v[k] - bv);
#pragma unroll
    for (int m = 1; m < 16; m <<= 1) s += __shfl_xor(s, m, 16);

    if (l == 0) {
        float cf  = conf[a];
        float sig = 1.0f / (1.0f + expf(-cf));
        float inv = 1.0f / s;            // == softmax at argmax (exp(0)/S)
        scores[a] = sig * inv;
        labels[a] = bi;
    }
}

// ---------------------------------------------------------------------------
// K2: per-batch full bitonic sort of 8192 u64 keys = (score_bits<<32) | ~idx.
// Descending keys == descending score, ties -> lowest index (lax.top_k order).
// ---------------------------------------------------------------------------
__global__ __launch_bounds__(1024) void k_sort(const float* __restrict__ scores,
                                               float* __restrict__ out_scores,
                                               int* __restrict__ top_idx) {
    __shared__ uint64_t key[NSORT];   // 64 KiB
    int b   = blockIdx.x;
    int tid = threadIdx.x;
    const float* sb = scores + (size_t)b * NM;

    for (int i = tid; i < NSORT; i += 1024) {
        uint64_t kk = 0;
        if (i < NM) {
            uint32_t sbits = __float_as_uint(sb[i]);   // scores > 0 -> bit-monotone
            kk = ((uint64_t)sbits << 32) | (uint32_t)(~(uint32_t)i);
        }
        key[i] = kk;
    }
    __syncthreads();

    for (int kk = 2; kk <= NSORT; kk <<= 1) {
        for (int j = kk >> 1; j > 0; j >>= 1) {
            for (int t = tid; t < NSORT / 2; t += 1024) {
                int i   = 2 * t - (t & (j - 1));
                int ixj = i + j;
                uint64_t a = key[i], c = key[ixj];
                bool up = (i & kk) == 0;
                bool sw = up ? (a < c) : (a > c);   // descending sort
                if (sw) { key[i] = c; key[ixj] = a; }
            }
            __syncthreads();
        }
    }

    for (int r = tid; r < NTOP; r += 1024) {
        uint64_t kk = key[r];
        out_scores[b * NTOP + r] = __uint_as_float((uint32_t)(kk >> 32));
        top_idx[b * NPAD + r]    = (int)(~(uint32_t)kk);
    }
}

// ---------------------------------------------------------------------------
// K3: gather top-1000 labels, decode + normalize + clip boxes.
// ---------------------------------------------------------------------------
__global__ __launch_bounds__(256) void k_decode(const int* __restrict__ top_idx,
                                                const int* __restrict__ labels,
                                                const float* __restrict__ reg,
                                                const float* __restrict__ anchors,
                                                const float* __restrict__ stridemap,
                                                float* __restrict__ out_labels,
                                                float* __restrict__ out_boxes,
                                                float* __restrict__ nbox,
                                                int* __restrict__ nlab) {
#pragma clang fp contract(off)
    int t = blockIdx.x * blockDim.x + threadIdx.x;
    if (t >= NB * NTOP) return;
    int b = t / NTOP, r = t % NTOP;
    int idx = top_idx[b * NPAD + r];
    int lab = labels[(size_t)b * NM + idx];
    out_labels[b * NTOP + r] = (float)lab;

    const float* rg = reg + ((size_t)b * NM + idx) * 4;
    float rx = rg[0], ry = rg[1], rw = rg[2], rh = rg[3];
    const float* an = anchors + (size_t)idx * 4;
    float ax = an[0], ay = an[1], aw = an[2], ah = an[3];
    float st = stridemap[idx];

    float sx = 1.0f / (1.0f + expf(-rx));
    float sy = 1.0f / (1.0f + expf(-ry));
    float cx = ax + sx * st;
    float cy = ay + sy * st;
    float w  = aw * expf(rw);
    float h  = ah * expf(rh);
    float x1 = cx - 0.5f * w, y1 = cy - 0.5f * h;
    float x2 = cx + 0.5f * w, y2 = cy + 0.5f * h;

    float nx1 = fminf(fmaxf(x1 / IMGSZ, 0.0f), 1.0f);
    float ny1 = fminf(fmaxf(y1 / IMGSZ, 0.0f), 1.0f);
    float nx2 = fminf(fmaxf(x2 / IMGSZ, 0.0f), 1.0f);
    float ny2 = fminf(fmaxf(y2 / IMGSZ, 0.0f), 1.0f);

    float4 bx = make_float4(nx1, ny1, nx2, ny2);
    ((float4*)out_boxes)[b * NTOP + r] = bx;
    ((float4*)nbox)[b * NPAD + r]      = bx;
    nlab[b * NPAD + r] = lab;
}

// ---------------------------------------------------------------------------
// K4: build column-major suppression bit-matrix.
// sup[b][tj][ti][j0] (u64 over ii): bit ii set iff i=ti*64+ii suppresses
// j=tj*64+j0  (i<j, same label, iou>0.6, both < NTOP). Only ti<=tj written.
// ---------------------------------------------------------------------------
__global__ __launch_bounds__(256) void k_supmat(const float* __restrict__ nbox,
                                                const int* __restrict__ nlab,
                                                uint64_t* __restrict__ sup) {
#pragma clang fp contract(off)
    __shared__ float4 sbx[NPAD];
    __shared__ float  sar[NPAD];
    __shared__ int    slb[NPAD];
    int b  = blockIdx.x >> 4;
    int tj = blockIdx.x & 15;
    int tid = threadIdx.x;

    for (int i = tid; i < NPAD; i += 256) {
        float4 v = ((const float4*)nbox)[b * NPAD + i];
        sbx[i] = v;
        sar[i] = (v.z - v.x) * (v.w - v.y);
        slb[i] = nlab[b * NPAD + i];
    }
    __syncthreads();

    int j0 = tid & 63;
    int wv = tid >> 6;           // 0..3
    int j  = tj * 64 + j0;
    float4 bj = sbx[j];
    float  aj = sar[j];
    int    lj = slb[j];
    bool jvalid = (j < NTOP);

    for (int ti = wv; ti <= tj; ti += 4) {
        uint64_t bits = 0;
        for (int ii = 0; ii < 64; ++ii) {
            int i = ti * 64 + ii;
            float4 bi = sbx[i];
            float  ai = sar[i];
            float xx1 = fmaxf(bi.x, bj.x);
            float yy1 = fmaxf(bi.y, bj.y);
            float xx2 = fminf(bi.z, bj.z);
            float yy2 = fminf(bi.w, bj.w);
            float inter = fmaxf(EPSF, xx2 - xx1) * fmaxf(EPSF, yy2 - yy1);
            float uni   = fmaxf(ai + aj - inter, EPSF);
            float iou   = inter / uni;
            bool sup_ij = (i < j) && (i < NTOP) && jvalid &&
                          (slb[i] == lj) && (iou > NMS_TH);
            bits |= ((uint64_t)(sup_ij ? 1u : 0u)) << ii;
        }
        sup[(((size_t)b * 16 + tj) * 16 + ti) * 64 + j0] = bits;
    }
}

// ---------------------------------------------------------------------------
// K5: greedy NMS scan. One wave per batch. Within each 64-block, Jacobi
// iteration of alive = ballot(cand && !(supcol & alive)) converges to the
// unique fixpoint == sequential greedy solution.
// ---------------------------------------------------------------------------
__global__ __launch_bounds__(64) void k_nms(const float* __restrict__ out_scores,
                                            const uint64_t* __restrict__ sup,
                                            float* __restrict__ out_keep) {
    __shared__ uint64_t Kw[16];
    int b  = blockIdx.x;
    int j0 = threadIdx.x;       // 0..63
    const uint64_t* supb = sup + (size_t)b * 16 * 16 * 64;

    for (int tj = 0; tj < 16; ++tj) {
        int pos = tj * 64 + j0;
        bool k0 = (pos < NTOP) && (out_scores[b * NTOP + pos] >= CONF_TH);

        uint64_t ext = 0;
        for (int ti = 0; ti < tj; ++ti) {
            uint64_t w = supb[((size_t)tj * 16 + ti) * 64 + j0];
            ext |= (w & Kw[ti]);
        }
        uint64_t wself = supb[((size_t)tj * 16 + tj) * 64 + j0];
        bool cand = k0 && (ext == 0ULL);

        uint64_t alive = __ballot(cand);
        for (int it = 0; it < 64; ++it) {
            bool dead = (wself & alive) != 0ULL;
            uint64_t na = __ballot(cand && !dead);
            if (na == alive) break;
            alive = na;
        }
        if (j0 == 0) Kw[tj] = alive;
        __syncthreads();

        if (pos < NTOP)
            out_keep[b * NTOP + pos] = ((alive >> j0) & 1ULL) ? 1.0f : 0.0f;
    }
}

// ---------------------------------------------------------------------------
extern "C" void kernel_launch(void* const* d_in, const int* in_sizes, int n_in,
                              void* d_out, int out_size, void* d_ws, size_t ws_size,
                              hipStream_t stream) {
    const float* conf = (const float*)d_in[0];
    const float* cls  = (const float*)d_in[1];
    const float* reg  = (const float*)d_in[2];
    const float* anch = (const float*)d_in[3];
    const float* strm = (const float*)d_in[4];

    float* out        = (float*)d_out;
    float* out_scores = out;
    float* out_labels = out + NB * NTOP;
    float* out_boxes  = out + 2 * NB * NTOP;
    float* out_keep   = out + 2 * NB * NTOP + NB * NTOP * 4;

    char* ws = (char*)d_ws;
    float*    scores = (float*)(ws + OFF_SCORES);
    int*      labels = (int*)(ws + OFF_LABELS);
    int*      tidx   = (int*)(ws + OFF_TIDX);
    float*    nbox   = (float*)(ws + OFF_NBOX);
    int*      nlab   = (int*)(ws + OFF_NLAB);
    uint64_t* sup    = (uint64_t*)(ws + OFF_SUP);

    k_score<<<(NB * NM * 16) / 256, 256, 0, stream>>>(conf, cls, scores, labels);
    k_sort<<<NB, 1024, 0, stream>>>(scores, out_scores, tidx);
    k_decode<<<(NB * NTOP + 255) / 256, 256, 0, stream>>>(tidx, labels, reg, anch, strm,
                                                          out_labels, out_boxes, nbox, nlab);
    k_supmat<<<NB * 16, 256, 0, stream>>>(nbox, nlab, sup);
    k_nms<<<NB, 64, 0, stream>>>(out_scores, sup, out_keep);
}

// Round 2
// 132.799 us; speedup vs baseline: 1.2867x; 1.2867x over previous
//
#include <hip/hip_runtime.h>
#include <stdint.h>

#define NB 32
#define NM 6300
#define NC 80
#define NTOP 1000
#define NPAD 1024
#define NCAND 2048
#define NBINS 4096
#define BDT 512

static constexpr float IMGSZ   = 320.0f;
static constexpr float CONF_TH = 0.05f;
static constexpr float NMS_TH  = 0.6f;
static constexpr float EPSF    = 1e-10f;

// ---- workspace layout (bytes) ----
static constexpr size_t OFF_SCORES = 0;                                    // f32 [NB*NM]
static constexpr size_t OFF_LABELS = OFF_SCORES + (size_t)NB * NM * 4;     // i32 [NB*NM]
static constexpr size_t OFF_TIDX   = OFF_LABELS + (size_t)NB * NM * 4;     // i32 [NB*NPAD]
static constexpr size_t OFF_NBOX   = OFF_TIDX   + (size_t)NB * NPAD * 4;   // f32 [NB*NPAD*4]
static constexpr size_t OFF_NLAB   = OFF_NBOX   + (size_t)NB * NPAD * 16;  // i32 [NB*NPAD]
static constexpr size_t OFF_SUP    = ((OFF_NLAB + (size_t)NB * NPAD * 4) + 1023) & ~(size_t)1023; // u64 [NB*16*16*64]

// ---------------------------------------------------------------------------
// K1: per-anchor score = sigmoid(conf) * max(softmax(cls)), label = argmax.
// 16 lanes per anchor; lanes read consecutive classes (coalesced).
// ---------------------------------------------------------------------------
__global__ __launch_bounds__(256) void k_score(const float* __restrict__ conf,
                                               const float* __restrict__ cls,
                                               float* __restrict__ scores,
                                               int* __restrict__ labels) {
#pragma clang fp contract(off)
    int t = blockIdx.x * blockDim.x + threadIdx.x;
    int a = t >> 4;          // anchor index in [0, NB*NM)
    int l = t & 15;
    if (a >= NB * NM) return;
    const float* row = cls + (size_t)a * NC;

    float v[5];
#pragma unroll
    for (int k = 0; k < 5; ++k) v[k] = row[l + 16 * k];

    // local max/argmax (ties -> lowest class index)
    float bv = v[0];
    int bi = l;
#pragma unroll
    for (int k = 1; k < 5; ++k) {
        int c = l + 16 * k;
        if (v[k] > bv) { bv = v[k]; bi = c; }
    }
    // 16-lane butterfly reduce (max value, min index on ties)
#pragma unroll
    for (int m = 1; m < 16; m <<= 1) {
        float ov = __shfl_xor(bv, m, 16);
        int   oi = __shfl_xor(bi, m, 16);
        if (ov > bv || (ov == bv && oi < bi)) { bv = ov; bi = oi; }
    }
    // sum of exp(x - max)
    float s = 0.0f;
#pragma unroll
    for (int k = 0; k < 5; ++k) s += expf(v[k] - bv);
#pragma unroll
    for (int m = 1; m < 16; m <<= 1) s += __shfl_xor(s, m, 16);

    if (l == 0) {
        float cf  = conf[a];
        float sig = 1.0f / (1.0f + expf(-cf));
        float inv = 1.0f / s;            // == softmax at argmax (exp(0)/S)
        scores[a] = sig * inv;
        labels[a] = bi;
    }
}

// ---------------------------------------------------------------------------
// K2: histogram-select top-k, one block per batch.
//  (a) 4096-bin LDS histogram of top-12 float bits (positive -> bit-monotone)
//  (b) wave-0 suffix-scan finds largest bin T with count(bin>=T) >= NTOP
//  (c) wave-aggregated compaction of candidates into 2048-slot key array
//  (d) bitonic sort 2048 u64 keys (score_bits<<32 | ~idx), emit top-1000.
// Exactly reproduces lax.top_k order (desc score, ties -> lowest index).
// ---------------------------------------------------------------------------
__global__ __launch_bounds__(BDT) void k_topk(const float* __restrict__ scores,
                                              float* __restrict__ out_scores,
                                              int* __restrict__ top_idx) {
    __shared__ uint32_t hist[NBINS];    // 16 KiB
    __shared__ uint64_t key[NCAND];     // 16 KiB
    __shared__ int scnt;
    __shared__ int sT;
    int b = blockIdx.x, tid = threadIdx.x;
    const float* sb = scores + (size_t)b * NM;

    for (int i = tid; i < NBINS; i += BDT) hist[i] = 0;
    for (int i = tid; i < NCAND; i += BDT) key[i] = 0;
    if (tid == 0) scnt = 0;
    __syncthreads();

    for (int i = tid; i < NM; i += BDT)
        atomicAdd(&hist[__float_as_uint(sb[i]) >> 20], 1u);
    __syncthreads();

    if (tid < 64) {
        int l = tid;
        uint32_t q = 0;
        for (int i = 0; i < 64; ++i) q += hist[l * 64 + i];
        // inclusive suffix sum across lanes: s[l] = sum_{k>=l} q[k]
        uint32_t s = q;
        for (int off = 1; off < 64; off <<= 1) {
            uint32_t o = __shfl_down(s, off);
            if (l + off < 64) s += o;
        }
        uint64_t m = __ballot(s >= (uint32_t)NTOP);
        int c = 63 - __clzll(m);               // chunk containing threshold
        uint32_t sc_ = __shfl(s, c);
        uint32_t qc  = __shfl(q, c);
        uint32_t tail = sc_ - qc;              // elements in bins >= (c+1)*64
        // pass 2: within chunk c
        uint32_t v = hist[c * 64 + l];
        uint32_t s2 = v;
        for (int off = 1; off < 64; off <<= 1) {
            uint32_t o = __shfl_down(s2, off);
            if (l + off < 64) s2 += o;
        }
        uint64_t m2 = __ballot(s2 + tail >= (uint32_t)NTOP);
        int T = c * 64 + (63 - __clzll(m2));
        if (l == 0) sT = T;
    }
    __syncthreads();

    uint32_t T = (uint32_t)sT;
    int lane = tid & 63;
    for (int i = tid; i < NM; i += BDT) {
        uint32_t bits = __float_as_uint(sb[i]);
        bool pred = (bits >> 20) >= T;
        uint64_t mask = __ballot(pred);
        if (pred) {
            int leader = __ffsll((unsigned long long)mask) - 1;
            int prefix = __popcll(mask & ((1ull << lane) - 1));
            int base = 0;
            if (lane == leader) base = atomicAdd(&scnt, (int)__popcll(mask));
            base = __shfl(base, leader);
            int pos = base + prefix;
            if (pos < NCAND)
                key[pos] = ((uint64_t)bits << 32) | (uint32_t)(~(uint32_t)i);
        }
    }
    __syncthreads();

    // bitonic sort, descending
    for (int kk = 2; kk <= NCAND; kk <<= 1) {
        for (int j = kk >> 1; j > 0; j >>= 1) {
            for (int t = tid; t < NCAND / 2; t += BDT) {
                int i   = 2 * t - (t & (j - 1));
                int ixj = i + j;
                uint64_t a = key[i], c2 = key[ixj];
                bool up = (i & kk) == 0;
                if (up ? (a < c2) : (a > c2)) { key[i] = c2; key[ixj] = a; }
            }
            __syncthreads();
        }
    }

    for (int r = tid; r < NTOP; r += BDT) {
        uint64_t kk2 = key[r];
        out_scores[b * NTOP + r] = __uint_as_float((uint32_t)(kk2 >> 32));
        top_idx[b * NPAD + r]    = (int)(~(uint32_t)kk2);
    }
}

// ---------------------------------------------------------------------------
// K3: gather top-1000 labels, decode + normalize + clip boxes.
// ---------------------------------------------------------------------------
__global__ __launch_bounds__(256) void k_decode(const int* __restrict__ top_idx,
                                                const int* __restrict__ labels,
                                                const float* __restrict__ reg,
                                                const float* __restrict__ anchors,
                                                const float* __restrict__ stridemap,
                                                float* __restrict__ out_labels,
                                                float* __restrict__ out_boxes,
                                                float* __restrict__ nbox,
                                                int* __restrict__ nlab) {
#pragma clang fp contract(off)
    int t = blockIdx.x * blockDim.x + threadIdx.x;
    if (t >= NB * NTOP) return;
    int b = t / NTOP, r = t % NTOP;
    int idx = top_idx[b * NPAD + r];
    int lab = labels[(size_t)b * NM + idx];
    out_labels[b * NTOP + r] = (float)lab;

    const float* rg = reg + ((size_t)b * NM + idx) * 4;
    float rx = rg[0], ry = rg[1], rw = rg[2], rh = rg[3];
    const float* an = anchors + (size_t)idx * 4;
    float ax = an[0], ay = an[1], aw = an[2], ah = an[3];
    float st = stridemap[idx];

    float sx = 1.0f / (1.0f + expf(-rx));
    float sy = 1.0f / (1.0f + expf(-ry));
    float cx = ax + sx * st;
    float cy = ay + sy * st;
    float w  = aw * expf(rw);
    float h  = ah * expf(rh);
    float x1 = cx - 0.5f * w, y1 = cy - 0.5f * h;
    float x2 = cx + 0.5f * w, y2 = cy + 0.5f * h;

    float nx1 = fminf(fmaxf(x1 / IMGSZ, 0.0f), 1.0f);
    float ny1 = fminf(fmaxf(y1 / IMGSZ, 0.0f), 1.0f);
    float nx2 = fminf(fmaxf(x2 / IMGSZ, 0.0f), 1.0f);
    float ny2 = fminf(fmaxf(y2 / IMGSZ, 0.0f), 1.0f);

    float4 bx = make_float4(nx1, ny1, nx2, ny2);
    ((float4*)out_boxes)[b * NTOP + r] = bx;
    ((float4*)nbox)[b * NPAD + r]      = bx;
    nlab[b * NPAD + r] = lab;
}

// ---------------------------------------------------------------------------
// K4: build column-major suppression bit-matrix.
// sup[b][tj][ti][j0] (u64 over ii): bit ii set iff i=ti*64+ii suppresses
// j=tj*64+j0  (i<j, same label, iou>0.6, both < NTOP). Only ti<=tj written.
// ---------------------------------------------------------------------------
__global__ __launch_bounds__(256) void k_supmat(const float* __restrict__ nbox,
                                                const int* __restrict__ nlab,
                                                uint64_t* __restrict__ sup) {
#pragma clang fp contract(off)
    __shared__ float4 sbx[NPAD];
    __shared__ float  sar[NPAD];
    __shared__ int    slb[NPAD];
    int b  = blockIdx.x >> 4;
    int tj = blockIdx.x & 15;
    int tid = threadIdx.x;

    for (int i = tid; i < NPAD; i += 256) {
        float4 v = ((const float4*)nbox)[b * NPAD + i];
        sbx[i] = v;
        sar[i] = (v.z - v.x) * (v.w - v.y);
        slb[i] = nlab[b * NPAD + i];
    }
    __syncthreads();

    int j0 = tid & 63;
    int wv = tid >> 6;           // 0..3
    int j  = tj * 64 + j0;
    float4 bj = sbx[j];
    float  aj = sar[j];
    int    lj = slb[j];
    bool jvalid = (j < NTOP);

    for (int ti = wv; ti <= tj; ti += 4) {
        uint64_t bits = 0;
        for (int ii = 0; ii < 64; ++ii) {
            int i = ti * 64 + ii;
            float4 bi = sbx[i];
            float  ai = sar[i];
            float xx1 = fmaxf(bi.x, bj.x);
            float yy1 = fmaxf(bi.y, bj.y);
            float xx2 = fminf(bi.z, bj.z);
            float yy2 = fminf(bi.w, bj.w);
            float inter = fmaxf(EPSF, xx2 - xx1) * fmaxf(EPSF, yy2 - yy1);
            float uni   = fmaxf(ai + aj - inter, EPSF);
            float iou   = inter / uni;
            bool sup_ij = (i < j) && (i < NTOP) && jvalid &&
                          (slb[i] == lj) && (iou > NMS_TH);
            bits |= ((uint64_t)(sup_ij ? 1u : 0u)) << ii;
        }
        sup[(((size_t)b * 16 + tj) * 16 + ti) * 64 + j0] = bits;
    }
}

// ---------------------------------------------------------------------------
// K5: greedy NMS scan. One wave per batch. Within each 64-block, Jacobi
// iteration of alive = ballot(cand && !(supcol & alive)) converges to the
// unique fixpoint == sequential greedy solution.
// ---------------------------------------------------------------------------
__global__ __launch_bounds__(64) void k_nms(const float* __restrict__ out_scores,
                                            const uint64_t* __restrict__ sup,
                                            float* __restrict__ out_keep) {
    __shared__ uint64_t Kw[16];
    int b  = blockIdx.x;
    int j0 = threadIdx.x;       // 0..63
    const uint64_t* supb = sup + (size_t)b * 16 * 16 * 64;

    for (int tj = 0; tj < 16; ++tj) {
        int pos = tj * 64 + j0;
        bool k0 = (pos < NTOP) && (out_scores[b * NTOP + pos] >= CONF_TH);

        uint64_t ext = 0;
        for (int ti = 0; ti < tj; ++ti) {
            uint64_t w = supb[((size_t)tj * 16 + ti) * 64 + j0];
            ext |= (w & Kw[ti]);
        }
        uint64_t wself = supb[((size_t)tj * 16 + tj) * 64 + j0];
        bool cand = k0 && (ext == 0ULL);

        uint64_t alive = __ballot(cand);
        for (int it = 0; it < 64; ++it) {
            bool dead = (wself & alive) != 0ULL;
            uint64_t na = __ballot(cand && !dead);
            if (na == alive) break;
            alive = na;
        }
        if (j0 == 0) Kw[tj] = alive;
        __syncthreads();

        if (pos < NTOP)
            out_keep[b * NTOP + pos] = ((alive >> j0) & 1ULL) ? 1.0f : 0.0f;
    }
}

// ---------------------------------------------------------------------------
extern "C" void kernel_launch(void* const* d_in, const int* in_sizes, int n_in,
                              void* d_out, int out_size, void* d_ws, size_t ws_size,
                              hipStream_t stream) {
    const float* conf = (const float*)d_in[0];
    const float* cls  = (const float*)d_in[1];
    const float* reg  = (const float*)d_in[2];
    const float* anch = (const float*)d_in[3];
    const float* strm = (const float*)d_in[4];

    float* out        = (float*)d_out;
    float* out_scores = out;
    float* out_labels = out + NB * NTOP;
    float* out_boxes  = out + 2 * NB * NTOP;
    float* out_keep   = out + 2 * NB * NTOP + NB * NTOP * 4;

    char* ws = (char*)d_ws;
    float*    scores = (float*)(ws + OFF_SCORES);
    int*      labels = (int*)(ws + OFF_LABELS);
    int*      tidx   = (int*)(ws + OFF_TIDX);
    float*    nbox   = (float*)(ws + OFF_NBOX);
    int*      nlab   = (int*)(ws + OFF_NLAB);
    uint64_t* sup    = (uint64_t*)(ws + OFF_SUP);

    k_score<<<(NB * NM * 16) / 256, 256, 0, stream>>>(conf, cls, scores, labels);
    k_topk<<<NB, BDT, 0, stream>>>(scores, out_scores, tidx);
    k_decode<<<(NB * NTOP + 255) / 256, 256, 0, stream>>>(tidx, labels, reg, anch, strm,
                                                          out_labels, out_boxes, nbox, nlab);
    k_supmat<<<NB * 16, 256, 0, stream>>>(nbox, nlab, sup);
    k_nms<<<NB, 64, 0, stream>>>(out_scores, sup, out_keep);
}

// Round 3
// 108.680 us; speedup vs baseline: 1.5722x; 1.2219x over previous
//
#include <hip/hip_runtime.h>
#include <stdint.h>

#define NB 32
#define NM 6300
#define NC 80
#define NTOP 1000
#define NPAD 1024
#define NCAND 2048
#define NBINS 4096
#define BDT 512

static constexpr float IMGSZ   = 320.0f;
static constexpr float CONF_TH = 0.05f;
static constexpr float NMS_TH  = 0.6f;
static constexpr float EPSF    = 1e-10f;

// ---- workspace layout (bytes) ----
static constexpr size_t OFF_SCORES = 0;                                    // f32 [NB*NM]
static constexpr size_t OFF_LABELS = OFF_SCORES + (size_t)NB * NM * 4;     // i32 [NB*NM]
static constexpr size_t OFF_TIDX   = OFF_LABELS + (size_t)NB * NM * 4;     // i32 [NB*NPAD]
static constexpr size_t OFF_NBOX   = OFF_TIDX   + (size_t)NB * NPAD * 4;   // f32 [NB*NPAD*4]
static constexpr size_t OFF_NLAB   = OFF_NBOX   + (size_t)NB * NPAD * 16;  // i32 [NB*NPAD]
static constexpr size_t OFF_SUP    = ((OFF_NLAB + (size_t)NB * NPAD * 4) + 1023) & ~(size_t)1023; // u64 [NB*16*16*64]

// ---------------------------------------------------------------------------
// K1: per-anchor score = sigmoid(conf) * max(softmax(cls)), label = argmax.
// 16 lanes per anchor; lanes read consecutive classes (coalesced).
// ---------------------------------------------------------------------------
__global__ __launch_bounds__(256) void k_score(const float* __restrict__ conf,
                                               const float* __restrict__ cls,
                                               float* __restrict__ scores,
                                               int* __restrict__ labels) {
#pragma clang fp contract(off)
    int t = blockIdx.x * blockDim.x + threadIdx.x;
    int a = t >> 4;          // anchor index in [0, NB*NM)
    int l = t & 15;
    if (a >= NB * NM) return;
    const float* row = cls + (size_t)a * NC;

    float v[5];
#pragma unroll
    for (int k = 0; k < 5; ++k) v[k] = row[l + 16 * k];

    // local max/argmax (ties -> lowest class index)
    float bv = v[0];
    int bi = l;
#pragma unroll
    for (int k = 1; k < 5; ++k) {
        int c = l + 16 * k;
        if (v[k] > bv) { bv = v[k]; bi = c; }
    }
    // 16-lane butterfly reduce (max value, min index on ties)
#pragma unroll
    for (int m = 1; m < 16; m <<= 1) {
        float ov = __shfl_xor(bv, m, 16);
        int   oi = __shfl_xor(bi, m, 16);
        if (ov > bv || (ov == bv && oi < bi)) { bv = ov; bi = oi; }
    }
    // sum of exp(x - max)
    float s = 0.0f;
#pragma unroll
    for (int k = 0; k < 5; ++k) s += expf(v[k] - bv);
#pragma unroll
    for (int m = 1; m < 16; m <<= 1) s += __shfl_xor(s, m, 16);

    if (l == 0) {
        float cf  = conf[a];
        float sig = 1.0f / (1.0f + expf(-cf));
        float inv = 1.0f / s;            // == softmax at argmax (exp(0)/S)
        scores[a] = sig * inv;
        labels[a] = bi;
    }
}

// ---------------------------------------------------------------------------
// K2: histogram-select top-k, one block per batch.
// ---------------------------------------------------------------------------
__global__ __launch_bounds__(BDT) void k_topk(const float* __restrict__ scores,
                                              float* __restrict__ out_scores,
                                              int* __restrict__ top_idx) {
    __shared__ uint32_t hist[NBINS];    // 16 KiB
    __shared__ uint64_t key[NCAND];     // 16 KiB
    __shared__ int scnt;
    __shared__ int sT;
    int b = blockIdx.x, tid = threadIdx.x;
    const float* sb = scores + (size_t)b * NM;

    for (int i = tid; i < NBINS; i += BDT) hist[i] = 0;
    for (int i = tid; i < NCAND; i += BDT) key[i] = 0;
    if (tid == 0) scnt = 0;
    __syncthreads();

    for (int i = tid; i < NM; i += BDT)
        atomicAdd(&hist[__float_as_uint(sb[i]) >> 20], 1u);
    __syncthreads();

    if (tid < 64) {
        int l = tid;
        uint32_t q = 0;
        for (int i = 0; i < 64; ++i) q += hist[l * 64 + i];
        // inclusive suffix sum across lanes: s[l] = sum_{k>=l} q[k]
        uint32_t s = q;
        for (int off = 1; off < 64; off <<= 1) {
            uint32_t o = __shfl_down(s, off);
            if (l + off < 64) s += o;
        }
        uint64_t m = __ballot(s >= (uint32_t)NTOP);
        int c = 63 - __clzll(m);               // chunk containing threshold
        uint32_t sc_ = __shfl(s, c);
        uint32_t qc  = __shfl(q, c);
        uint32_t tail = sc_ - qc;              // elements in bins >= (c+1)*64
        // pass 2: within chunk c
        uint32_t v = hist[c * 64 + l];
        uint32_t s2 = v;
        for (int off = 1; off < 64; off <<= 1) {
            uint32_t o = __shfl_down(s2, off);
            if (l + off < 64) s2 += o;
        }
        uint64_t m2 = __ballot(s2 + tail >= (uint32_t)NTOP);
        int T = c * 64 + (63 - __clzll(m2));
        if (l == 0) sT = T;
    }
    __syncthreads();

    uint32_t T = (uint32_t)sT;
    int lane = tid & 63;
    for (int i = tid; i < NM; i += BDT) {
        uint32_t bits = __float_as_uint(sb[i]);
        bool pred = (bits >> 20) >= T;
        uint64_t mask = __ballot(pred);
        if (pred) {
            int leader = __ffsll((unsigned long long)mask) - 1;
            int prefix = __popcll(mask & ((1ull << lane) - 1));
            int base = 0;
            if (lane == leader) base = atomicAdd(&scnt, (int)__popcll(mask));
            base = __shfl(base, leader);
            int pos = base + prefix;
            if (pos < NCAND)
                key[pos] = ((uint64_t)bits << 32) | (uint32_t)(~(uint32_t)i);
        }
    }
    __syncthreads();

    // bitonic sort, descending
    for (int kk = 2; kk <= NCAND; kk <<= 1) {
        for (int j = kk >> 1; j > 0; j >>= 1) {
            for (int t = tid; t < NCAND / 2; t += BDT) {
                int i   = 2 * t - (t & (j - 1));
                int ixj = i + j;
                uint64_t a = key[i], c2 = key[ixj];
                bool up = (i & kk) == 0;
                if (up ? (a < c2) : (a > c2)) { key[i] = c2; key[ixj] = a; }
            }
            __syncthreads();
        }
    }

    for (int r = tid; r < NTOP; r += BDT) {
        uint64_t kk2 = key[r];
        out_scores[b * NTOP + r] = __uint_as_float((uint32_t)(kk2 >> 32));
        top_idx[b * NPAD + r]    = (int)(~(uint32_t)kk2);
    }
}

// ---------------------------------------------------------------------------
// K3: gather top-1000 labels, decode + normalize + clip boxes.
// ---------------------------------------------------------------------------
__global__ __launch_bounds__(256) void k_decode(const int* __restrict__ top_idx,
                                                const int* __restrict__ labels,
                                                const float* __restrict__ reg,
                                                const float* __restrict__ anchors,
                                                const float* __restrict__ stridemap,
                                                float* __restrict__ out_labels,
                                                float* __restrict__ out_boxes,
                                                float* __restrict__ nbox,
                                                int* __restrict__ nlab) {
#pragma clang fp contract(off)
    int t = blockIdx.x * blockDim.x + threadIdx.x;
    if (t >= NB * NTOP) return;
    int b = t / NTOP, r = t % NTOP;
    int idx = top_idx[b * NPAD + r];
    int lab = labels[(size_t)b * NM + idx];
    out_labels[b * NTOP + r] = (float)lab;

    const float* rg = reg + ((size_t)b * NM + idx) * 4;
    float rx = rg[0], ry = rg[1], rw = rg[2], rh = rg[3];
    const float* an = anchors + (size_t)idx * 4;
    float ax = an[0], ay = an[1], aw = an[2], ah = an[3];
    float st = stridemap[idx];

    float sx = 1.0f / (1.0f + expf(-rx));
    float sy = 1.0f / (1.0f + expf(-ry));
    float cx = ax + sx * st;
    float cy = ay + sy * st;
    float w  = aw * expf(rw);
    float h  = ah * expf(rh);
    float x1 = cx - 0.5f * w, y1 = cy - 0.5f * h;
    float x2 = cx + 0.5f * w, y2 = cy + 0.5f * h;

    float nx1 = fminf(fmaxf(x1 / IMGSZ, 0.0f), 1.0f);
    float ny1 = fminf(fmaxf(y1 / IMGSZ, 0.0f), 1.0f);
    float nx2 = fminf(fmaxf(x2 / IMGSZ, 0.0f), 1.0f);
    float ny2 = fminf(fmaxf(y2 / IMGSZ, 0.0f), 1.0f);

    float4 bx = make_float4(nx1, ny1, nx2, ny2);
    ((float4*)out_boxes)[b * NTOP + r] = bx;
    ((float4*)nbox)[b * NPAD + r]      = bx;
    nlab[b * NPAD + r] = lab;
}

// ---------------------------------------------------------------------------
// K4: suppression bit-matrix, one WAVE per 64x64 tile (flat triangular grid).
// Lane = row i (box in regs); loop jj broadcasts box j from LDS; the output
// word for column j is exactly __ballot(pred). 136 tiles x 32 batches =
// 4352 balanced waves (~17/CU).
// sup[b][tj][ti][j0] (u64 over ii): bit ii set iff i=ti*64+ii suppresses
// j=tj*64+j0  (i<j, same label, iou>0.6, both < NTOP). Only ti<=tj written.
// ---------------------------------------------------------------------------
__global__ __launch_bounds__(64) void k_supmat(const float* __restrict__ nbox,
                                               const int* __restrict__ nlab,
                                               uint64_t* __restrict__ sup) {
#pragma clang fp contract(off)
    __shared__ float4 sbj[64];
    __shared__ float  saj[64];
    __shared__ int    slj[64];
    int b = blockIdx.y;
    int t = blockIdx.x;                 // 0..135 triangular pair index
    int tj = (int)((sqrtf(8.0f * (float)t + 1.0f) - 1.0f) * 0.5f);
    while ((tj + 1) * (tj + 2) / 2 <= t) ++tj;   // fixup vs sqrt rounding
    while (tj * (tj + 1) / 2 > t) --tj;
    int ti = t - tj * (tj + 1) / 2;

    int lane = threadIdx.x;
    int i = ti * 64 + lane;
    int j = tj * 64 + lane;

    float4 bj = ((const float4*)nbox)[b * NPAD + j];
    sbj[lane] = bj;
    saj[lane] = (bj.z - bj.x) * (bj.w - bj.y);
    slj[lane] = nlab[b * NPAD + j];

    float4 bi = ((const float4*)nbox)[b * NPAD + i];
    float ai = (bi.z - bi.x) * (bi.w - bi.y);
    int   li = nlab[b * NPAD + i];
    bool ivalid = (i < NTOP);
    __syncthreads();

    uint64_t mybits = 0;
    for (int jj = 0; jj < 64; ++jj) {
        float4 bjv = sbj[jj];           // same-address broadcast reads
        float  ajv = saj[jj];
        int    ljv = slj[jj];
        int    jg  = tj * 64 + jj;
        float xx1 = fmaxf(bi.x, bjv.x);
        float yy1 = fmaxf(bi.y, bjv.y);
        float xx2 = fminf(bi.z, bjv.z);
        float yy2 = fminf(bi.w, bjv.w);
        float inter = fmaxf(EPSF, xx2 - xx1) * fmaxf(EPSF, yy2 - yy1);
        float uni   = fmaxf(ai + ajv - inter, EPSF);
        float iou   = inter / uni;
        bool sup_ij = (i < jg) && ivalid && (jg < NTOP) &&
                      (li == ljv) && (iou > NMS_TH);
        uint64_t bal = __ballot(sup_ij);
        if (lane == jj) mybits = bal;
    }
    sup[(((size_t)b * 16 + tj) * 16 + ti) * 64 + lane] = mybits;
}

// ---------------------------------------------------------------------------
// K5: greedy NMS scan. One wave per batch. Within each 64-block, Jacobi
// iteration of alive = ballot(cand && !(supcol & alive)) converges to the
// unique fixpoint == sequential greedy solution.
// ---------------------------------------------------------------------------
__global__ __launch_bounds__(64) void k_nms(const float* __restrict__ out_scores,
                                            const uint64_t* __restrict__ sup,
                                            float* __restrict__ out_keep) {
    __shared__ uint64_t Kw[16];
    int b  = blockIdx.x;
    int j0 = threadIdx.x;       // 0..63
    const uint64_t* supb = sup + (size_t)b * 16 * 16 * 64;

    for (int tj = 0; tj < 16; ++tj) {
        int pos = tj * 64 + j0;
        bool k0 = (pos < NTOP) && (out_scores[b * NTOP + pos] >= CONF_TH);

        uint64_t ext = 0;
        for (int ti = 0; ti < tj; ++ti) {
            uint64_t w = supb[((size_t)tj * 16 + ti) * 64 + j0];
            ext |= (w & Kw[ti]);
        }
        uint64_t wself = supb[((size_t)tj * 16 + tj) * 64 + j0];
        bool cand = k0 && (ext == 0ULL);

        uint64_t alive = __ballot(cand);
        for (int it = 0; it < 64; ++it) {
            bool dead = (wself & alive) != 0ULL;
            uint64_t na = __ballot(cand && !dead);
            if (na == alive) break;
            alive = na;
        }
        if (j0 == 0) Kw[tj] = alive;
        __syncthreads();

        if (pos < NTOP)
            out_keep[b * NTOP + pos] = ((alive >> j0) & 1ULL) ? 1.0f : 0.0f;
    }
}

// ---------------------------------------------------------------------------
extern "C" void kernel_launch(void* const* d_in, const int* in_sizes, int n_in,
                              void* d_out, int out_size, void* d_ws, size_t ws_size,
                              hipStream_t stream) {
    const float* conf = (const float*)d_in[0];
    const float* cls  = (const float*)d_in[1];
    const float* reg  = (const float*)d_in[2];
    const float* anch = (const float*)d_in[3];
    const float* strm = (const float*)d_in[4];

    float* out        = (float*)d_out;
    float* out_scores = out;
    float* out_labels = out + NB * NTOP;
    float* out_boxes  = out + 2 * NB * NTOP;
    float* out_keep   = out + 2 * NB * NTOP + NB * NTOP * 4;

    char* ws = (char*)d_ws;
    float*    scores = (float*)(ws + OFF_SCORES);
    int*      labels = (int*)(ws + OFF_LABELS);
    int*      tidx   = (int*)(ws + OFF_TIDX);
    float*    nbox   = (float*)(ws + OFF_NBOX);
    int*      nlab   = (int*)(ws + OFF_NLAB);
    uint64_t* sup    = (uint64_t*)(ws + OFF_SUP);

    k_score<<<(NB * NM * 16) / 256, 256, 0, stream>>>(conf, cls, scores, labels);
    k_topk<<<NB, BDT, 0, stream>>>(scores, out_scores, tidx);
    k_decode<<<(NB * NTOP + 255) / 256, 256, 0, stream>>>(tidx, labels, reg, anch, strm,
                                                          out_labels, out_boxes, nbox, nlab);
    k_supmat<<<dim3(136, NB), 64, 0, stream>>>(nbox, nlab, sup);
    k_nms<<<NB, 64, 0, stream>>>(out_scores, sup, out_keep);
}

// Round 4
// 70.883 us; speedup vs baseline: 2.4106x; 1.5332x over previous
//
#include <hip/hip_runtime.h>
#include <stdint.h>

#define NB 32
#define NM 6300
#define NC 80
#define NTOP 1000
#define NPAD 1024
#define NCAND 2048
#define NBINS 4096
#define BDT 1024

static constexpr float IMGSZ   = 320.0f;
static constexpr float CONF_TH = 0.05f;
static constexpr float NMS_TH  = 0.6f;
static constexpr float EPSF    = 1e-10f;

// ---- workspace layout (bytes) ----
static constexpr size_t OFF_SCORES = 0;                                    // f32 [NB*NM]
static constexpr size_t OFF_LABELS = OFF_SCORES + (size_t)NB * NM * 4;     // i32 [NB*NM]
static constexpr size_t OFF_TIDX   = OFF_LABELS + (size_t)NB * NM * 4;     // i32 [NB*NPAD]
static constexpr size_t OFF_NBOX   = OFF_TIDX   + (size_t)NB * NPAD * 4;   // f32 [NB*NPAD*4]
static constexpr size_t OFF_NLAB   = OFF_NBOX   + (size_t)NB * NPAD * 16;  // i32 [NB*NPAD]
static constexpr size_t OFF_SUP    = ((OFF_NLAB + (size_t)NB * NPAD * 4) + 1023) & ~(size_t)1023; // u64 [NB*16*16*64]

// ---------------------------------------------------------------------------
// K1: per-anchor score = sigmoid(conf) * max(softmax(cls)), label = argmax.
// ---------------------------------------------------------------------------
__global__ __launch_bounds__(256) void k_score(const float* __restrict__ conf,
                                               const float* __restrict__ cls,
                                               float* __restrict__ scores,
                                               int* __restrict__ labels) {
#pragma clang fp contract(off)
    int t = blockIdx.x * blockDim.x + threadIdx.x;
    int a = t >> 4;          // anchor index in [0, NB*NM)
    int l = t & 15;
    if (a >= NB * NM) return;
    const float* row = cls + (size_t)a * NC;

    float v[5];
#pragma unroll
    for (int k = 0; k < 5; ++k) v[k] = row[l + 16 * k];

    float bv = v[0];
    int bi = l;
#pragma unroll
    for (int k = 1; k < 5; ++k) {
        int c = l + 16 * k;
        if (v[k] > bv) { bv = v[k]; bi = c; }
    }
#pragma unroll
    for (int m = 1; m < 16; m <<= 1) {
        float ov = __shfl_xor(bv, m, 16);
        int   oi = __shfl_xor(bi, m, 16);
        if (ov > bv || (ov == bv && oi < bi)) { bv = ov; bi = oi; }
    }
    float s = 0.0f;
#pragma unroll
    for (int k = 0; k < 5; ++k) s += expf(v[k] - bv);
#pragma unroll
    for (int m = 1; m < 16; m <<= 1) s += __shfl_xor(s, m, 16);

    if (l == 0) {
        float cf  = conf[a];
        float sig = 1.0f / (1.0f + expf(-cf));
        float inv = 1.0f / s;
        scores[a] = sig * inv;
        labels[a] = bi;
    }
}

// ---------------------------------------------------------------------------
// K2: histogram-select top-k, one block (1024 thr) per batch.
// ---------------------------------------------------------------------------
__global__ __launch_bounds__(BDT) void k_topk(const float* __restrict__ scores,
                                              float* __restrict__ out_scores,
                                              int* __restrict__ top_idx) {
    __shared__ uint32_t hist[NBINS];    // 16 KiB
    __shared__ uint64_t key[NCAND];     // 16 KiB
    __shared__ int scnt;
    __shared__ int sT;
    int b = blockIdx.x, tid = threadIdx.x;
    const float* sb = scores + (size_t)b * NM;

    for (int i = tid; i < NBINS; i += BDT) hist[i] = 0;
    for (int i = tid; i < NCAND; i += BDT) key[i] = 0;
    if (tid == 0) scnt = 0;
    __syncthreads();

    for (int i = tid; i < NM; i += BDT)
        atomicAdd(&hist[__float_as_uint(sb[i]) >> 20], 1u);
    __syncthreads();

    if (tid < 64) {
        int l = tid;
        uint32_t q = 0;
        for (int i = 0; i < 64; ++i) q += hist[l * 64 + i];
        uint32_t s = q;
        for (int off = 1; off < 64; off <<= 1) {
            uint32_t o = __shfl_down(s, off);
            if (l + off < 64) s += o;
        }
        uint64_t m = __ballot(s >= (uint32_t)NTOP);
        int c = 63 - __clzll(m);
        uint32_t sc_ = __shfl(s, c);
        uint32_t qc  = __shfl(q, c);
        uint32_t tail = sc_ - qc;
        uint32_t v = hist[c * 64 + l];
        uint32_t s2 = v;
        for (int off = 1; off < 64; off <<= 1) {
            uint32_t o = __shfl_down(s2, off);
            if (l + off < 64) s2 += o;
        }
        uint64_t m2 = __ballot(s2 + tail >= (uint32_t)NTOP);
        int T = c * 64 + (63 - __clzll(m2));
        if (l == 0) sT = T;
    }
    __syncthreads();

    uint32_t T = (uint32_t)sT;
    int lane = tid & 63;
    for (int i = tid; i < NM; i += BDT) {
        uint32_t bits = __float_as_uint(sb[i]);
        bool pred = (bits >> 20) >= T;
        uint64_t mask = __ballot(pred);
        if (pred) {
            int leader = __ffsll((unsigned long long)mask) - 1;
            int prefix = __popcll(mask & ((1ull << lane) - 1));
            int base = 0;
            if (lane == leader) base = atomicAdd(&scnt, (int)__popcll(mask));
            base = __shfl(base, leader);
            int pos = base + prefix;
            if (pos < NCAND)
                key[pos] = ((uint64_t)bits << 32) | (uint32_t)(~(uint32_t)i);
        }
    }
    __syncthreads();

    for (int kk = 2; kk <= NCAND; kk <<= 1) {
        for (int j = kk >> 1; j > 0; j >>= 1) {
            for (int t = tid; t < NCAND / 2; t += BDT) {
                int i   = 2 * t - (t & (j - 1));
                int ixj = i + j;
                uint64_t a = key[i], c2 = key[ixj];
                bool up = (i & kk) == 0;
                if (up ? (a < c2) : (a > c2)) { key[i] = c2; key[ixj] = a; }
            }
            __syncthreads();
        }
    }

    for (int r = tid; r < NTOP; r += BDT) {
        uint64_t kk2 = key[r];
        out_scores[b * NTOP + r] = __uint_as_float((uint32_t)(kk2 >> 32));
        top_idx[b * NPAD + r]    = (int)(~(uint32_t)kk2);
    }
}

// ---------------------------------------------------------------------------
// K3: gather top-1000 labels, decode + normalize + clip boxes.
// ---------------------------------------------------------------------------
__global__ __launch_bounds__(256) void k_decode(const int* __restrict__ top_idx,
                                                const int* __restrict__ labels,
                                                const float* __restrict__ reg,
                                                const float* __restrict__ anchors,
                                                const float* __restrict__ stridemap,
                                                float* __restrict__ out_labels,
                                                float* __restrict__ out_boxes,
                                                float* __restrict__ nbox,
                                                int* __restrict__ nlab) {
#pragma clang fp contract(off)
    int t = blockIdx.x * blockDim.x + threadIdx.x;
    if (t >= NB * NTOP) return;
    int b = t / NTOP, r = t % NTOP;
    int idx = top_idx[b * NPAD + r];
    int lab = labels[(size_t)b * NM + idx];
    out_labels[b * NTOP + r] = (float)lab;

    const float* rg = reg + ((size_t)b * NM + idx) * 4;
    float rx = rg[0], ry = rg[1], rw = rg[2], rh = rg[3];
    const float* an = anchors + (size_t)idx * 4;
    float ax = an[0], ay = an[1], aw = an[2], ah = an[3];
    float st = stridemap[idx];

    float sx = 1.0f / (1.0f + expf(-rx));
    float sy = 1.0f / (1.0f + expf(-ry));
    float cx = ax + sx * st;
    float cy = ay + sy * st;
    float w  = aw * expf(rw);
    float h  = ah * expf(rh);
    float x1 = cx - 0.5f * w, y1 = cy - 0.5f * h;
    float x2 = cx + 0.5f * w, y2 = cy + 0.5f * h;

    float nx1 = fminf(fmaxf(x1 / IMGSZ, 0.0f), 1.0f);
    float ny1 = fminf(fmaxf(y1 / IMGSZ, 0.0f), 1.0f);
    float nx2 = fminf(fmaxf(x2 / IMGSZ, 0.0f), 1.0f);
    float ny2 = fminf(fmaxf(y2 / IMGSZ, 0.0f), 1.0f);

    float4 bx = make_float4(nx1, ny1, nx2, ny2);
    ((float4*)out_boxes)[b * NTOP + r] = bx;
    ((float4*)nbox)[b * NPAD + r]      = bx;
    nlab[b * NPAD + r] = lab;
}

// ---------------------------------------------------------------------------
// K4: suppression bit-matrix. One wave per (64x64 tile, 32-column half).
// Box j broadcast via __shfl (uniform index -> readlane), no LDS in loop.
// sup[b][tj][ti][j0]: bit ii set iff i=ti*64+ii suppresses j=tj*64+j0.
// ---------------------------------------------------------------------------
__global__ __launch_bounds__(64) void k_supmat(const float* __restrict__ nbox,
                                               const int* __restrict__ nlab,
                                               uint64_t* __restrict__ sup) {
#pragma clang fp contract(off)
    int b  = blockIdx.y;
    int bx = blockIdx.x;                // 0..271
    int t  = bx >> 1;                   // triangular pair index 0..135
    int h  = bx & 1;                    // column half
    int tj = (int)((sqrtf(8.0f * (float)t + 1.0f) - 1.0f) * 0.5f);
    while ((tj + 1) * (tj + 2) / 2 <= t) ++tj;
    while (tj * (tj + 1) / 2 > t) --tj;
    int ti = t - tj * (tj + 1) / 2;

    int lane = threadIdx.x;
    int i = ti * 64 + lane;
    int j = tj * 64 + lane;

    float4 bi = ((const float4*)nbox)[b * NPAD + i];
    float  ai = (bi.z - bi.x) * (bi.w - bi.y);
    int    li = nlab[b * NPAD + i];
    float4 bj = ((const float4*)nbox)[b * NPAD + j];
    float  aj = (bj.z - bj.x) * (bj.w - bj.y);
    int    lj = nlab[b * NPAD + j];
    bool ivalid = (i < NTOP);

    uint64_t mybits = 0;
#pragma unroll 8
    for (int u = 0; u < 32; ++u) {
        int jj = h * 32 + u;
        float bjx = __shfl(bj.x, jj);
        float bjy = __shfl(bj.y, jj);
        float bjz = __shfl(bj.z, jj);
        float bjw = __shfl(bj.w, jj);
        float ajv = __shfl(aj, jj);
        int   ljv = __shfl(lj, jj);
        int   jg  = tj * 64 + jj;
        float xx1 = fmaxf(bi.x, bjx);
        float yy1 = fmaxf(bi.y, bjy);
        float xx2 = fminf(bi.z, bjz);
        float yy2 = fminf(bi.w, bjw);
        float inter = fmaxf(EPSF, xx2 - xx1) * fmaxf(EPSF, yy2 - yy1);
        float uni   = fmaxf(ai + ajv - inter, EPSF);
        float iou   = inter / uni;
        bool sup_ij = (i < jg) && ivalid && (jg < NTOP) &&
                      (li == ljv) && (iou > NMS_TH);
        uint64_t bal = __ballot(sup_ij);
        if (lane == jj) mybits = bal;
    }
    if ((lane >> 5) == h)
        sup[(((size_t)b * 16 + tj) * 16 + ti) * 64 + lane] = mybits;
}

// ---------------------------------------------------------------------------
// K5: greedy NMS scan, 16 waves per batch (wave w = column-block tj=w).
// Each wave preloads its sup rows into registers (static unroll), then a
// 16-step pipelined scan: step s = wave s Jacobi -> Kw[s] via LDS -> barrier
// -> waves w>s fold wrow[s]&Kw[s] into ext. Jacobi fixpoint == greedy.
// ---------------------------------------------------------------------------
__global__ __launch_bounds__(1024) void k_nms(const float* __restrict__ out_scores,
                                              const uint64_t* __restrict__ sup,
                                              float* __restrict__ out_keep) {
    __shared__ uint64_t Kw[16];
    int b    = blockIdx.x;
    int w    = threadIdx.x >> 6;    // wave id = tj block
    int lane = threadIdx.x & 63;
    const uint64_t* supb = sup + (size_t)b * 16 * 16 * 64;

    uint64_t wrow[16];
#pragma unroll
    for (int ti = 0; ti < 16; ++ti)
        wrow[ti] = (ti <= w) ? supb[((size_t)w * 16 + ti) * 64 + lane] : 0ULL;

    int pos = w * 64 + lane;
    bool k0 = (pos < NTOP) && (out_scores[b * NTOP + pos] >= CONF_TH);

    uint64_t ext = 0;
#pragma unroll
    for (int s = 0; s < 16; ++s) {
        if (w == s) {
            bool cand = k0 && (ext == 0ULL);
            uint64_t wself = wrow[s];          // == wrow[w] here (static idx)
            uint64_t alive = __ballot(cand);
            for (int it = 0; it < 64; ++it) {
                bool dead = (wself & alive) != 0ULL;
                uint64_t na = __ballot(cand && !dead);
                if (na == alive) break;
                alive = na;
            }
            if (lane == 0) Kw[s] = alive;
            if (pos < NTOP)
                out_keep[b * NTOP + pos] = ((alive >> lane) & 1ULL) ? 1.0f : 0.0f;
        }
        __syncthreads();
        if (w > s) ext |= wrow[s] & Kw[s];
    }
}

// ---------------------------------------------------------------------------
extern "C" void kernel_launch(void* const* d_in, const int* in_sizes, int n_in,
                              void* d_out, int out_size, void* d_ws, size_t ws_size,
                              hipStream_t stream) {
    const float* conf = (const float*)d_in[0];
    const float* cls  = (const float*)d_in[1];
    const float* reg  = (const float*)d_in[2];
    const float* anch = (const float*)d_in[3];
    const float* strm = (const float*)d_in[4];

    float* out        = (float*)d_out;
    float* out_scores = out;
    float* out_labels = out + NB * NTOP;
    float* out_boxes  = out + 2 * NB * NTOP;
    float* out_keep   = out + 2 * NB * NTOP + NB * NTOP * 4;

    char* ws = (char*)d_ws;
    float*    scores = (float*)(ws + OFF_SCORES);
    int*      labels = (int*)(ws + OFF_LABELS);
    int*      tidx   = (int*)(ws + OFF_TIDX);
    float*    nbox   = (float*)(ws + OFF_NBOX);
    int*      nlab   = (int*)(ws + OFF_NLAB);
    uint64_t* sup    = (uint64_t*)(ws + OFF_SUP);

    k_score<<<(NB * NM * 16) / 256, 256, 0, stream>>>(conf, cls, scores, labels);
    k_topk<<<NB, BDT, 0, stream>>>(scores, out_scores, tidx);
    k_decode<<<(NB * NTOP + 255) / 256, 256, 0, stream>>>(tidx, labels, reg, anch, strm,
                                                          out_labels, out_boxes, nbox, nlab);
    k_supmat<<<dim3(272, NB), 64, 0, stream>>>(nbox, nlab, sup);
    k_nms<<<NB, 1024, 0, stream>>>(out_scores, sup, out_keep);
}